// Round 1
// baseline (12577.550 us; speedup 1.0000x reference)
//
#include <hip/hip_runtime.h>
#include <cstdint>
#include <cstddef>

// Problem constants (from reference)
constexpr int Dm   = 1024;   // model dim
constexpr int NH   = 16;     // heads
constexpr int DK   = 64;     // head dim
constexpr int Bb   = 4;      // batch
constexpr int TLEN = 512;    // tgt len
constexpr int SLEN = 256;    // src len
constexpr int NL   = 8;      // layers
constexpr int FFd  = 4096;   // ffn dim
constexpr int Vv   = 32000;  // vocab

// ---------------------------------------------------------------------------
// Positional encoding value for (pos s, channel d), D = 1024
__device__ __forceinline__ float pe_val(int s, int d) {
  // div = exp(-(2i) * ln(10000)/D); even d -> sin, odd d -> cos (same i)
  float e = -(float)(d & ~1) * (9.210340371976184f / (float)Dm);
  float freq = expf(e);
  float ang = (float)s * freq;
  return (d & 1) ? cosf(ang) : sinf(ang);
}

__global__ __launch_bounds__(256) void embed_pe_kernel(
    const float* __restrict__ emb, const int* __restrict__ tgt,
    float* __restrict__ x) {
  int idx = blockIdx.x * 256 + threadIdx.x;   // < Bb*TLEN*Dm
  int bs = idx >> 10;                          // b*TLEN + s
  int d  = idx & 1023;
  int s  = bs & (TLEN - 1);
  int tok = tgt[bs];
  x[idx] = emb[(size_t)tok * Dm + d] + pe_val(s, d);
}

__global__ __launch_bounds__(256) void src_pe_kernel(
    const float* __restrict__ src, float* __restrict__ enc) {
  int idx = blockIdx.x * 256 + threadIdx.x;   // < Bb*SLEN*Dm
  int d = idx & 1023;
  int s = (idx >> 10) & (SLEN - 1);
  enc[idx] = src[idx] + pe_val(s, d);
}

// ---------------------------------------------------------------------------
// Block-wide reduction helper. op: 0 = sum, 1 = max. red must hold >= 4 floats.
__device__ __forceinline__ float block_reduce(float v, int op, float* red) {
#pragma unroll
  for (int off = 32; off > 0; off >>= 1) {
    float o = __shfl_down(v, off, 64);
    v = op ? fmaxf(v, o) : (v + o);
  }
  int tid = threadIdx.x;
  int nw = blockDim.x >> 6;   // waves per block
  if ((tid & 63) == 0) red[tid >> 6] = v;
  __syncthreads();
  float r = red[0];
  for (int i = 1; i < nw; i++) r = op ? fmaxf(r, red[i]) : (r + red[i]);
  __syncthreads();            // make red reusable
  return r;
}

// ---------------------------------------------------------------------------
// C[M,N] = A[M,K] @ B[K,N] + bias[N]  (optional relu). Row-major everything.
// 64x64 tile, K-tile 16, 256 threads, 4x4 accum per thread.
__global__ __launch_bounds__(256) void gemm_bias_kernel(
    const float* __restrict__ A, const float* __restrict__ B,
    const float* __restrict__ bias, float* __restrict__ C,
    int M, int N, int K, int relu) {
  __shared__ float As[16][64];
  __shared__ float Bs[16][64];
  int tid = threadIdx.x;
  int tx4 = (tid & 15) << 2;
  int ty4 = (tid >> 4) << 2;
  int col0 = blockIdx.x << 6;
  int row0 = blockIdx.y << 6;
  int ar = tid >> 2, ac = (tid & 3) << 2;   // A tile: row ar (0..63), cols ac..ac+3
  int br = tid >> 4;                         // B tile: row br (0..15), cols tx4..tx4+3
  const float* Ap = A + (size_t)(row0 + ar) * K + ac;
  const float* Bp = B + (size_t)br * N + col0 + tx4;
  float acc[4][4] = {{0.f}};
  for (int k0 = 0; k0 < K; k0 += 16) {
    float4 a4 = *(const float4*)(Ap + k0);
    float4 b4 = *(const float4*)(Bp + (size_t)k0 * N);
    As[ac + 0][ar] = a4.x; As[ac + 1][ar] = a4.y;
    As[ac + 2][ar] = a4.z; As[ac + 3][ar] = a4.w;
    *(float4*)&Bs[br][tx4] = b4;
    __syncthreads();
#pragma unroll
    for (int kk = 0; kk < 16; ++kk) {
      float4 a = *(const float4*)&As[kk][ty4];
      float4 b = *(const float4*)&Bs[kk][tx4];
      float av[4] = {a.x, a.y, a.z, a.w};
      float bv[4] = {b.x, b.y, b.z, b.w};
#pragma unroll
      for (int i = 0; i < 4; ++i)
#pragma unroll
        for (int j = 0; j < 4; ++j)
          acc[i][j] = fmaf(av[i], bv[j], acc[i][j]);
    }
    __syncthreads();
  }
  float4 bsv = *(const float4*)(bias + col0 + tx4);
  float bvv[4] = {bsv.x, bsv.y, bsv.z, bsv.w};
#pragma unroll
  for (int i = 0; i < 4; ++i) {
    float4 o;
    float* op = (float*)&o;
#pragma unroll
    for (int j = 0; j < 4; ++j) {
      float v = acc[i][j] + bvv[j];
      if (relu) v = fmaxf(v, 0.f);
      op[j] = v;
    }
    *(float4*)(C + (size_t)(row0 + ty4 + i) * N + col0 + tx4) = o;
  }
}

// ---------------------------------------------------------------------------
// scores[bh, q, k] = scale * dot(Q[b,q,h*64:...], K[b,k,h*64:...])
// grid: (Sk/64, Sq/64, B*NH)
__global__ __launch_bounds__(256) void attn_scores_kernel(
    const float* __restrict__ Q, const float* __restrict__ Km,
    float* __restrict__ S, int Sq, int Sk, float scale) {
  __shared__ float Qs[16][64];
  __shared__ float Ks[16][64];
  int tid = threadIdx.x;
  int tx4 = (tid & 15) << 2;
  int ty4 = (tid >> 4) << 2;
  int bh = blockIdx.z;
  int b = bh >> 4, h = bh & 15;
  int k0g = blockIdx.x << 6;
  int q0g = blockIdx.y << 6;
  const float* Qb = Q + (size_t)b * Sq * Dm + (size_t)h * DK;
  const float* Kb = Km + (size_t)b * Sk * Dm + (size_t)h * DK;
  float* Sb = S + (size_t)bh * Sq * Sk;
  int ar = tid >> 2, ac = (tid & 3) << 2;
  float acc[4][4] = {{0.f}};
  for (int d0 = 0; d0 < DK; d0 += 16) {
    float4 a4 = *(const float4*)(Qb + (size_t)(q0g + ar) * Dm + d0 + ac);
    float4 b4 = *(const float4*)(Kb + (size_t)(k0g + ar) * Dm + d0 + ac);
    Qs[ac + 0][ar] = a4.x; Qs[ac + 1][ar] = a4.y;
    Qs[ac + 2][ar] = a4.z; Qs[ac + 3][ar] = a4.w;
    Ks[ac + 0][ar] = b4.x; Ks[ac + 1][ar] = b4.y;
    Ks[ac + 2][ar] = b4.z; Ks[ac + 3][ar] = b4.w;
    __syncthreads();
#pragma unroll
    for (int kk = 0; kk < 16; ++kk) {
      float4 a = *(const float4*)&Qs[kk][ty4];
      float4 b = *(const float4*)&Ks[kk][tx4];
      float av[4] = {a.x, a.y, a.z, a.w};
      float bv[4] = {b.x, b.y, b.z, b.w};
#pragma unroll
      for (int i = 0; i < 4; ++i)
#pragma unroll
        for (int j = 0; j < 4; ++j)
          acc[i][j] = fmaf(av[i], bv[j], acc[i][j]);
    }
    __syncthreads();
  }
#pragma unroll
  for (int i = 0; i < 4; ++i) {
    float4 o;
    o.x = acc[i][0] * scale; o.y = acc[i][1] * scale;
    o.z = acc[i][2] * scale; o.w = acc[i][3] * scale;
    *(float4*)(Sb + (size_t)(q0g + ty4 + i) * Sk + k0g + tx4) = o;
  }
}

// ---------------------------------------------------------------------------
// In-place masked softmax over last dim. grid: B*NH*TLEN rows.
// causal=1: self-attn mask = (tgt[b,q] != 0) && (k <= q); causal=0: no mask.
__global__ __launch_bounds__(256) void softmax_mask_kernel(
    float* __restrict__ S, const int* __restrict__ tgt, int Sk, int causal) {
  __shared__ float buf[TLEN];
  __shared__ float red[4];
  int r = blockIdx.x;            // ((b*NH + h)*TLEN + q)
  int q = r & (TLEN - 1);
  int b = r >> 13;               // / (NH*TLEN)
  float* row = S + (size_t)r * Sk;
  int tid = threadIdx.x;
  bool row_valid = true;
  if (causal) row_valid = (tgt[b * TLEN + q] != 0);
  float lmax = -3.4e38f;
  for (int i = tid; i < Sk; i += 256) {
    float v = row[i];
    if (causal && (!row_valid || i > q)) v = -1e9f;
    buf[i] = v;
    lmax = fmaxf(lmax, v);
  }
  float gmax = block_reduce(lmax, 1, red);
  float lsum = 0.f;
  for (int i = tid; i < Sk; i += 256) {
    float e = __expf(buf[i] - gmax);
    buf[i] = e;
    lsum += e;
  }
  float gsum = block_reduce(lsum, 0, red);
  float inv = 1.0f / gsum;
  for (int i = tid; i < Sk; i += 256) row[i] = buf[i] * inv;
}

// ---------------------------------------------------------------------------
// O[b, q, h*64+n] = sum_k P[bh, q, k] * V[b, k, h*64+n]
// grid: (Sq/64, B*NH). N = 64 (one tile).
__global__ __launch_bounds__(256) void attn_pv_kernel(
    const float* __restrict__ P, const float* __restrict__ V,
    float* __restrict__ O, int Sq, int Sk) {
  __shared__ float Ps[16][64];
  __shared__ float Vs[16][64];
  int tid = threadIdx.x;
  int tx4 = (tid & 15) << 2;
  int ty4 = (tid >> 4) << 2;
  int bh = blockIdx.y;
  int b = bh >> 4, h = bh & 15;
  int q0 = blockIdx.x << 6;
  const float* Pb = P + (size_t)bh * Sq * Sk;
  const float* Vb = V + (size_t)b * Sk * Dm + (size_t)h * DK;
  float* Ob = O + (size_t)b * Sq * Dm + (size_t)h * DK;
  int ar = tid >> 2, ac = (tid & 3) << 2;
  int br = tid >> 4;
  float acc[4][4] = {{0.f}};
  for (int k0 = 0; k0 < Sk; k0 += 16) {
    float4 a4 = *(const float4*)(Pb + (size_t)(q0 + ar) * Sk + k0 + ac);
    float4 b4 = *(const float4*)(Vb + (size_t)(k0 + br) * Dm + tx4);
    Ps[ac + 0][ar] = a4.x; Ps[ac + 1][ar] = a4.y;
    Ps[ac + 2][ar] = a4.z; Ps[ac + 3][ar] = a4.w;
    *(float4*)&Vs[br][tx4] = b4;
    __syncthreads();
#pragma unroll
    for (int kk = 0; kk < 16; ++kk) {
      float4 a = *(const float4*)&Ps[kk][ty4];
      float4 b = *(const float4*)&Vs[kk][tx4];
      float av[4] = {a.x, a.y, a.z, a.w};
      float bv[4] = {b.x, b.y, b.z, b.w};
#pragma unroll
      for (int i = 0; i < 4; ++i)
#pragma unroll
        for (int j = 0; j < 4; ++j)
          acc[i][j] = fmaf(av[i], bv[j], acc[i][j]);
    }
    __syncthreads();
  }
#pragma unroll
  for (int i = 0; i < 4; ++i) {
    float4 o;
    o.x = acc[i][0]; o.y = acc[i][1]; o.z = acc[i][2]; o.w = acc[i][3];
    *(float4*)(Ob + (size_t)(q0 + ty4 + i) * Dm + tx4) = o;
  }
}

// ---------------------------------------------------------------------------
// x = LayerNorm(x + a) * g + b   (row = one token, D = 1024)
__global__ __launch_bounds__(256) void add_ln_kernel(
    float* __restrict__ x, const float* __restrict__ a,
    const float* __restrict__ g, const float* __restrict__ be) {
  __shared__ float buf[Dm];
  __shared__ float red[4];
  int r = blockIdx.x;
  float* xr = x + (size_t)r * Dm;
  const float* ar = a + (size_t)r * Dm;
  int tid = threadIdx.x;
  float ls = 0.f;
  for (int i = tid; i < Dm; i += 256) {
    float v = xr[i] + ar[i];
    buf[i] = v;
    ls += v;
  }
  float mu = block_reduce(ls, 0, red) * (1.0f / Dm);
  float lv = 0.f;
  for (int i = tid; i < Dm; i += 256) {
    float d = buf[i] - mu;
    lv += d * d;
  }
  float var = block_reduce(lv, 0, red) * (1.0f / Dm);
  float inv = rsqrtf(var + 1e-5f);
  for (int i = tid; i < Dm; i += 256)
    xr[i] = (buf[i] - mu) * inv * g[i] + be[i];
}

// ---------------------------------------------------------------------------
extern "C" void kernel_launch(void* const* d_in, const int* in_sizes, int n_in,
                              void* d_out, int out_size, void* d_ws, size_t ws_size,
                              hipStream_t stream) {
  // setup_inputs() dict order:
  const float* src  = (const float*)d_in[0];
  const int*   tgt  = (const int*)  d_in[1];
  const float* emb  = (const float*)d_in[2];
  const float* fc_w = (const float*)d_in[3];
  const float* fc_b = (const float*)d_in[4];
  const float* sa_wq = (const float*)d_in[5];
  const float* sa_bq = (const float*)d_in[6];
  const float* sa_wk = (const float*)d_in[7];
  const float* sa_bk = (const float*)d_in[8];
  const float* sa_wv = (const float*)d_in[9];
  const float* sa_bv = (const float*)d_in[10];
  const float* sa_wo = (const float*)d_in[11];
  const float* sa_bo = (const float*)d_in[12];
  const float* ca_wq = (const float*)d_in[13];
  const float* ca_bq = (const float*)d_in[14];
  const float* ca_wk = (const float*)d_in[15];
  const float* ca_bk = (const float*)d_in[16];
  const float* ca_wv = (const float*)d_in[17];
  const float* ca_bv = (const float*)d_in[18];
  const float* ca_wo = (const float*)d_in[19];
  const float* ca_bo = (const float*)d_in[20];
  const float* w1   = (const float*)d_in[21];
  const float* b1   = (const float*)d_in[22];
  const float* w2   = (const float*)d_in[23];
  const float* b2   = (const float*)d_in[24];
  const float* n1g  = (const float*)d_in[25];
  const float* n2g  = (const float*)d_in[26];
  const float* n3g  = (const float*)d_in[27];
  const float* n1b  = (const float*)d_in[28];
  const float* n2b  = (const float*)d_in[29];
  const float* n3b  = (const float*)d_in[30];
  float* out = (float*)d_out;

  // Workspace carve-up (floats)
  float* ws = (float*)d_ws;
  const size_t encN   = (size_t)Bb * SLEN * Dm;   // 1M
  const size_t xN     = (size_t)Bb * TLEN * Dm;   // 2M
  float* enc    = ws;
  float* x      = enc + encN;
  float* qb     = x + xN;
  float* kb     = qb + xN;
  float* vb     = kb + xN;
  float* attnb  = vb + xN;
  float* projb  = attnb + xN;
  float* ffh    = projb + xN;                     // 2048*4096
  float* scores = ffh + (size_t)Bb * TLEN * FFd;  // 4*16*512*512

  const int M  = Bb * TLEN;   // 2048 decoder tokens
  const int Me = Bb * SLEN;   // 1024 encoder tokens
  dim3 blk(256);

  embed_pe_kernel<<<(Bb * TLEN * Dm) / 256, blk, 0, stream>>>(emb, tgt, x);
  src_pe_kernel<<<(Bb * SLEN * Dm) / 256, blk, 0, stream>>>(src, enc);

  const float scale = 0.125f;   // 1/sqrt(64)

  for (int l = 0; l < NL; ++l) {
    const size_t wOff = (size_t)l * Dm * Dm;
    const size_t bOff = (size_t)l * Dm;

    // ---- self attention ----
    gemm_bias_kernel<<<dim3(Dm / 64, M / 64), blk, 0, stream>>>(
        x, sa_wq + wOff, sa_bq + bOff, qb, M, Dm, Dm, 0);
    gemm_bias_kernel<<<dim3(Dm / 64, M / 64), blk, 0, stream>>>(
        x, sa_wk + wOff, sa_bk + bOff, kb, M, Dm, Dm, 0);
    gemm_bias_kernel<<<dim3(Dm / 64, M / 64), blk, 0, stream>>>(
        x, sa_wv + wOff, sa_bv + bOff, vb, M, Dm, Dm, 0);
    attn_scores_kernel<<<dim3(TLEN / 64, TLEN / 64, Bb * NH), blk, 0, stream>>>(
        qb, kb, scores, TLEN, TLEN, scale);
    softmax_mask_kernel<<<Bb * NH * TLEN, blk, 0, stream>>>(scores, tgt, TLEN, 1);
    attn_pv_kernel<<<dim3(TLEN / 64, Bb * NH), blk, 0, stream>>>(
        scores, vb, attnb, TLEN, TLEN);
    gemm_bias_kernel<<<dim3(Dm / 64, M / 64), blk, 0, stream>>>(
        attnb, sa_wo + wOff, sa_bo + bOff, projb, M, Dm, Dm, 0);
    add_ln_kernel<<<M, blk, 0, stream>>>(x, projb, n1g + bOff, n1b + bOff);

    // ---- cross attention ----
    gemm_bias_kernel<<<dim3(Dm / 64, M / 64), blk, 0, stream>>>(
        x, ca_wq + wOff, ca_bq + bOff, qb, M, Dm, Dm, 0);
    gemm_bias_kernel<<<dim3(Dm / 64, Me / 64), blk, 0, stream>>>(
        enc, ca_wk + wOff, ca_bk + bOff, kb, Me, Dm, Dm, 0);
    gemm_bias_kernel<<<dim3(Dm / 64, Me / 64), blk, 0, stream>>>(
        enc, ca_wv + wOff, ca_bv + bOff, vb, Me, Dm, Dm, 0);
    attn_scores_kernel<<<dim3(SLEN / 64, TLEN / 64, Bb * NH), blk, 0, stream>>>(
        qb, kb, scores, TLEN, SLEN, scale);
    softmax_mask_kernel<<<Bb * NH * TLEN, blk, 0, stream>>>(scores, tgt, SLEN, 0);
    attn_pv_kernel<<<dim3(TLEN / 64, Bb * NH), blk, 0, stream>>>(
        scores, vb, attnb, TLEN, SLEN);
    gemm_bias_kernel<<<dim3(Dm / 64, M / 64), blk, 0, stream>>>(
        attnb, ca_wo + wOff, ca_bo + bOff, projb, M, Dm, Dm, 0);
    add_ln_kernel<<<M, blk, 0, stream>>>(x, projb, n2g + bOff, n2b + bOff);

    // ---- feed forward ----
    gemm_bias_kernel<<<dim3(FFd / 64, M / 64), blk, 0, stream>>>(
        x, w1 + (size_t)l * Dm * FFd, b1 + (size_t)l * FFd, ffh, M, FFd, Dm, 1);
    gemm_bias_kernel<<<dim3(Dm / 64, M / 64), blk, 0, stream>>>(
        ffh, w2 + (size_t)l * FFd * Dm, b2 + bOff, projb, M, Dm, FFd, 0);
    add_ln_kernel<<<M, blk, 0, stream>>>(x, projb, n3g + bOff, n3b + bOff);
  }

  // ---- final projection to vocab ----
  gemm_bias_kernel<<<dim3(Vv / 64, M / 64), blk, 0, stream>>>(
      x, fc_w, fc_b, out, M, Vv, Dm, 0);
}